// Round 12
// baseline (990.952 us; speedup 1.0000x reference)
//
#include <hip/hip_runtime.h>

#define EMB 128
#define CAP 128      // bucket capacity per node; deg~Poisson(32), P(>128)~1e-40
#define CSTRIDE 4    // counter padding stride in ints (4 counters per 64B line)
#define NPART 16     // dst-range partitions for fill (3.2MB window, L2-fits; R10-proven)

typedef _Float16 half2_t __attribute__((ext_vector_type(2)));

// ---- bf16 helpers ---------------------------------------------------------
__device__ inline unsigned short f2bf(float f) {
    union { float f; unsigned u; } v; v.f = f;
    unsigned r = v.u + 0x7FFF + ((v.u >> 16) & 1);
    return (unsigned short)(r >> 16);
}
__device__ inline float bf2f(unsigned short b) {
    union { unsigned u; float f; } v; v.u = ((unsigned)b) << 16;
    return v.f;
}
// ---- f16 helpers ----------------------------------------------------------
__device__ inline unsigned short f2h(float f) {
    _Float16 h = (_Float16)f;
    return __builtin_bit_cast(unsigned short, h);
}
__device__ inline float fdot2u(unsigned a, unsigned b, float c) {
#if __has_builtin(__builtin_amdgcn_fdot2)
    return __builtin_amdgcn_fdot2(__builtin_bit_cast(half2_t, a),
                                  __builtin_bit_cast(half2_t, b), c, false);
#else
    half2_t ha = __builtin_bit_cast(half2_t, a);
    half2_t hb = __builtin_bit_cast(half2_t, b);
    return c + (float)ha.x * (float)hb.x + (float)ha.y * (float)hb.y;
#endif
}

// ---- partitioned bucket fill (R10 config: 16 partitions, NT streaming) ----
__global__ void k_fillb(const int* __restrict__ src, const int* __restrict__ dst,
                        int* __restrict__ cnt, int* __restrict__ cs, int E, int N) {
    const int part = blockIdx.x & (NPART - 1);
    const int lo = (int)(((long long)N * part) / NPART);
    const int hi = (int)(((long long)N * (part + 1)) / NPART);
    int i = (int)(blockIdx.x >> 4) * blockDim.x + threadIdx.x;
    const int stride = (int)(gridDim.x >> 4) * blockDim.x;
    for (; i < E; i += stride) {
        const int d = __builtin_nontemporal_load(&dst[i]);
        if (d >= lo && d < hi) {
            const int s = __builtin_nontemporal_load(&src[i]);
            int p = atomicAdd(&cnt[(size_t)d * CSTRIDE], 1);
            if (p < CAP) cs[((size_t)d << 7) + p] = s;
        }
    }
}

// ---- norm = 1/sqrt(max(deg,1)), norm2 = norm*norm -------------------------
__global__ void k_norm(const int* __restrict__ cnt, float* __restrict__ nrm,
                       float* __restrict__ nrm2, int N) {
    int i = blockIdx.x * blockDim.x + threadIdx.x;
    if (i < N) {
        float d = fmaxf((float)cnt[(size_t)i * CSTRIDE], 1.0f);
        float r = 1.0f / sqrtf(d);
        nrm[i] = r;
        nrm2[i] = r * r;
    }
}

// ---- X0 = emb * nrm -> bf16, quarter-split layout [4][N][32] ---------------
__global__ void k_scale_bf(const float* __restrict__ x, const float* __restrict__ s,
                           ushort4* __restrict__ o, int N, int total4) {
    int idx = blockIdx.x * blockDim.x + threadIdx.x;
    if (idx < total4) {
        const int node = idx >> 5;   // 32 float4 per 128-float row
        const int q = idx & 31;
        const int qu = q >> 3;       // which quarter (8 float4 per quarter)
        const int wi = q & 7;
        const float4 v = ((const float4*)x)[idx];
        const float f = s[node];
        ushort4 r;
        r.x = f2bf(v.x * f); r.y = f2bf(v.y * f);
        r.z = f2bf(v.z * f); r.w = f2bf(v.w * f);
        o[((size_t)qu * N + node) * 8 + wi] = r;
    }
}

// ---- hop on one 32-dim quarter, bf16 -> bf16: 8 lanes per node -------------
__global__ __launch_bounds__(256) void k_hop_bb(const ushort4* __restrict__ in_q,
                                                const float* __restrict__ oscale,
                                                const int* __restrict__ cnt,
                                                const int* __restrict__ csr,
                                                ushort4* __restrict__ out_q, int N) {
    const int l = threadIdx.x & 7;
    int nd = (blockIdx.x * blockDim.x + threadIdx.x) >> 3;
    const int nnd = (gridDim.x * blockDim.x) >> 3;
    for (int i = nd; i < N; i += nnd) {
        const int jb = i << 7;
        const int je = jb + min(cnt[(size_t)i * CSTRIDE], CAP);
        float ax = 0.f, ay = 0.f, az = 0.f, aw = 0.f;
        int j = jb;
        for (; j + 4 <= je; j += 4) {
            const int c0 = csr[j], c1 = csr[j + 1], c2 = csr[j + 2], c3 = csr[j + 3];
            const ushort4 v0 = in_q[(size_t)c0 * 8 + l];
            const ushort4 v1 = in_q[(size_t)c1 * 8 + l];
            const ushort4 v2 = in_q[(size_t)c2 * 8 + l];
            const ushort4 v3 = in_q[(size_t)c3 * 8 + l];
            ax += bf2f(v0.x) + bf2f(v1.x) + bf2f(v2.x) + bf2f(v3.x);
            ay += bf2f(v0.y) + bf2f(v1.y) + bf2f(v2.y) + bf2f(v3.y);
            az += bf2f(v0.z) + bf2f(v1.z) + bf2f(v2.z) + bf2f(v3.z);
            aw += bf2f(v0.w) + bf2f(v1.w) + bf2f(v2.w) + bf2f(v3.w);
        }
        for (; j < je; ++j) {
            const ushort4 v = in_q[(size_t)csr[j] * 8 + l];
            ax += bf2f(v.x); ay += bf2f(v.y); az += bf2f(v.z); aw += bf2f(v.w);
        }
        const float s = oscale[i];
        ushort4 o;
        o.x = f2bf(ax * s); o.y = f2bf(ay * s);
        o.z = f2bf(az * s); o.w = f2bf(aw * s);
        out_q[(size_t)i * 8 + l] = o;
    }
}

// ---- hop on one quarter, bf16 -> f32 ---------------------------------------
__global__ __launch_bounds__(256) void k_hop_bf(const ushort4* __restrict__ in_q,
                                                const float* __restrict__ oscale,
                                                const int* __restrict__ cnt,
                                                const int* __restrict__ csr,
                                                float4* __restrict__ out_q, int N) {
    const int l = threadIdx.x & 7;
    int nd = (blockIdx.x * blockDim.x + threadIdx.x) >> 3;
    const int nnd = (gridDim.x * blockDim.x) >> 3;
    for (int i = nd; i < N; i += nnd) {
        const int jb = i << 7;
        const int je = jb + min(cnt[(size_t)i * CSTRIDE], CAP);
        float ax = 0.f, ay = 0.f, az = 0.f, aw = 0.f;
        int j = jb;
        for (; j + 4 <= je; j += 4) {
            const int c0 = csr[j], c1 = csr[j + 1], c2 = csr[j + 2], c3 = csr[j + 3];
            const ushort4 v0 = in_q[(size_t)c0 * 8 + l];
            const ushort4 v1 = in_q[(size_t)c1 * 8 + l];
            const ushort4 v2 = in_q[(size_t)c2 * 8 + l];
            const ushort4 v3 = in_q[(size_t)c3 * 8 + l];
            ax += bf2f(v0.x) + bf2f(v1.x) + bf2f(v2.x) + bf2f(v3.x);
            ay += bf2f(v0.y) + bf2f(v1.y) + bf2f(v2.y) + bf2f(v3.y);
            az += bf2f(v0.z) + bf2f(v1.z) + bf2f(v2.z) + bf2f(v3.z);
            aw += bf2f(v0.w) + bf2f(v1.w) + bf2f(v2.w) + bf2f(v3.w);
        }
        for (; j < je; ++j) {
            const ushort4 v = in_q[(size_t)csr[j] * 8 + l];
            ax += bf2f(v.x); ay += bf2f(v.y); az += bf2f(v.z); aw += bf2f(v.w);
        }
        const float s = oscale[i];
        float4 o; o.x = ax * s; o.y = ay * s; o.z = az * s; o.w = aw * s;
        out_q[(size_t)i * 8 + l] = o;
    }
}

// ---- linear: y(f16, half-split) = h(quarter-split f32) @ W.T + bias --------
#define LIN_RT 128
__global__ __launch_bounds__(256) void k_lin(const float* __restrict__ H2,
                                             const float* __restrict__ W,
                                             const float* __restrict__ bias,
                                             unsigned short* __restrict__ y, int N) {
    __shared__ float Wl[128 * 128];
    __shared__ float hl[LIN_RT * 129];
    const int t = threadIdx.x;
    const int r0g = blockIdx.x * LIN_RT;
    const int nv = min(LIN_RT, N - r0g);

    {
        const int j = t & 127, k0 = (t >> 7) * 64;
        #pragma unroll
        for (int c = 0; c < 16; ++c) {
            const float4 v = *(const float4*)&W[j * 128 + k0 + 4 * c];
            Wl[(k0 + 4 * c + 0) * 128 + j] = v.x;
            Wl[(k0 + 4 * c + 1) * 128 + j] = v.y;
            Wl[(k0 + 4 * c + 2) * 128 + j] = v.z;
            Wl[(k0 + 4 * c + 3) * 128 + j] = v.w;
        }
    }
    for (int e = t; e < LIN_RT * 32; e += 256) {
        const int r = e >> 5, q = e & 31;
        const int qu = q >> 3, wi = q & 7;   // quarter-split H2
        float4 v; v.x = 0.f; v.y = 0.f; v.z = 0.f; v.w = 0.f;
        if (r < nv)
            v = *(const float4*)&H2[(((size_t)qu * N + r0g + r) * 8 + wi) * 4];
        hl[r * 129 + 4 * q + 0] = v.x;
        hl[r * 129 + 4 * q + 1] = v.y;
        hl[r * 129 + 4 * q + 2] = v.z;
        hl[r * 129 + 4 * q + 3] = v.w;
    }
    __syncthreads();

    const int tc = t & 15, tr = t >> 4;
    const int rb = tr * 8;
    const int j0 = 4 * tc, j1 = 64 + 4 * tc;
    float acc[8][8];
    #pragma unroll
    for (int a = 0; a < 8; ++a)
        #pragma unroll
        for (int b = 0; b < 8; ++b) acc[a][b] = 0.f;

    #pragma unroll 2
    for (int k = 0; k < 128; ++k) {
        const float4 w0 = *(const float4*)&Wl[k * 128 + j0];
        const float4 w1 = *(const float4*)&Wl[k * 128 + j1];
        float hreg[8];
        #pragma unroll
        for (int a = 0; a < 8; ++a) hreg[a] = hl[(rb + a) * 129 + k];
        #pragma unroll
        for (int a = 0; a < 8; ++a) {
            acc[a][0] += hreg[a] * w0.x; acc[a][1] += hreg[a] * w0.y;
            acc[a][2] += hreg[a] * w0.z; acc[a][3] += hreg[a] * w0.w;
            acc[a][4] += hreg[a] * w1.x; acc[a][5] += hreg[a] * w1.y;
            acc[a][6] += hreg[a] * w1.z; acc[a][7] += hreg[a] * w1.w;
        }
    }

    ushort4* y0 = (ushort4*)y;                       // dims 0-63
    ushort4* y1 = (ushort4*)(y + (size_t)N * 64);    // dims 64-127
    const float4 b0 = *(const float4*)&bias[j0];
    const float4 b1 = *(const float4*)&bias[j1];
    #pragma unroll
    for (int a = 0; a < 8; ++a) {
        const int r = rb + a;
        if (r < nv) {
            ushort4 p0, p1;
            p0.x = f2h(acc[a][0] + b0.x); p0.y = f2h(acc[a][1] + b0.y);
            p0.z = f2h(acc[a][2] + b0.z); p0.w = f2h(acc[a][3] + b0.w);
            p1.x = f2h(acc[a][4] + b1.x); p1.y = f2h(acc[a][5] + b1.y);
            p1.z = f2h(acc[a][6] + b1.z); p1.w = f2h(acc[a][7] + b1.w);
            y0[(size_t)(r0g + r) * 16 + tc] = p0;
            y1[(size_t)(r0g + r) * 16 + tc] = p1;
        }
    }
}

// ---- edge dots on one 64-dim half: 8 lanes x uint4 per edge, 8 edges/wave -
__global__ __launch_bounds__(256) void k_dot_h(const uint4* __restrict__ yh,
                                               const int* __restrict__ src,
                                               const int* __restrict__ dst,
                                               const int* __restrict__ nsrc,
                                               const int* __restrict__ ndst,
                                               float* __restrict__ out, int E,
                                               int accum) {
    const int lane = threadIdx.x & 63;
    const int grp = lane >> 3;           // 8 edges per wave
    const int l = lane & 7;              // 8 lanes per edge (8 x 16B = 128B row)
    int w = (blockIdx.x * blockDim.x + threadIdx.x) >> 6;
    const int nw = (gridDim.x * blockDim.x) >> 6;
    const int total = 2 * E;
    const int Q = (total + 7) >> 3;
    for (int q = w; q < Q; q += nw) {
        const int e = 8 * q + grp;
        if (e < total) {
            int s, d;
            if (e < E) { s = src[e]; d = dst[e]; }
            else       { s = nsrc[e - E]; d = ndst[e - E]; }
            const uint4 a = yh[(size_t)s * 8 + l];
            const uint4 c = yh[(size_t)d * 8 + l];
            float v0 = fdot2u(a.x, c.x, 0.f);
            float v1 = fdot2u(a.y, c.y, 0.f);
            v0 = fdot2u(a.z, c.z, v0);
            v1 = fdot2u(a.w, c.w, v1);
            float v = v0 + v1;
            v += __shfl_xor(v, 4);
            v += __shfl_xor(v, 2);
            v += __shfl_xor(v, 1);
            if (l == 0) out[e] = accum ? (out[e] + v) : v;
        }
    }
}

extern "C" void kernel_launch(void* const* d_in, const int* in_sizes, int n_in,
                              void* d_out, int out_size, void* d_ws, size_t ws_size,
                              hipStream_t stream) {
    const float* emb = (const float*)d_in[0];
    const float* W   = (const float*)d_in[1];
    const float* bia = (const float*)d_in[2];
    const int* src   = (const int*)d_in[3];
    const int* dst   = (const int*)d_in[4];
    const int* nsrc  = (const int*)d_in[5];
    const int* ndst  = (const int*)d_in[6];
    const int N = in_sizes[0] / EMB;
    const int E = in_sizes[3];
    float* out = (float*)d_out;

    const size_t szBF = (size_t)N * EMB * sizeof(unsigned short);  // 25.6 MB
    const size_t szF  = (size_t)N * EMB * sizeof(float);           // 51.2 MB
    const size_t szCS = (size_t)N * CAP * sizeof(int);             // 51.2 MB
    const size_t szN  = (size_t)N * sizeof(int);

    char* p = (char*)d_ws;
    auto alloc = [&](size_t bytes) { char* r = p; p += (bytes + 255) & ~(size_t)255; return r; };
    unsigned short* X0  = (unsigned short*)alloc(szBF);  // [4][N][32] bf16; y overlays
    unsigned short* H1  = (unsigned short*)alloc(szBF);  // [4][N][32] bf16
    float*          H2  = (float*)alloc(szF);            // [4][N][32] f32
    int*   csr  = (int*)alloc(szCS);                     // bucket CSR
    float* nrm  = (float*)alloc(szN);
    float* nrm2 = (float*)alloc(szN);
    int*   cnt  = (int*)alloc(szN * CSTRIDE);            // padded counters
    unsigned short* ybf = X0;  // X0 dead after hop1 passes; y = [2][N][64] f16

    hipMemsetAsync(cnt, 0, szN * CSTRIDE, stream);
    k_fillb<<<2048, 256, 0, stream>>>(src, dst, cnt, csr, E, N);
    k_norm<<<(N + 255) / 256, 256, 0, stream>>>(cnt, nrm, nrm2, N);

    const int total4 = N * 32;
    k_scale_bf<<<(total4 + 255) / 256, 256, 0, stream>>>(emb, nrm, (ushort4*)X0, N, total4);

    const int NQ_BLOCKS = (N * 8 + 255) / 256;           // 8 lanes per node
    const ushort4* X0u = (const ushort4*)X0;
    ushort4* H1u = (ushort4*)H1;
    float4* H2u = (float4*)H2;
    for (int q = 0; q < 4; ++q)
        k_hop_bb<<<NQ_BLOCKS, 256, 0, stream>>>(X0u + (size_t)q * N * 8, nrm2, cnt, csr,
                                                H1u + (size_t)q * N * 8, N);
    for (int q = 0; q < 4; ++q)
        k_hop_bf<<<NQ_BLOCKS, 256, 0, stream>>>((const ushort4*)H1 + (size_t)q * N * 8,
                                                nrm, cnt, csr,
                                                H2u + (size_t)q * N * 8, N);

    k_lin<<<(N + LIN_RT - 1) / LIN_RT, 256, 0, stream>>>(H2, W, bia, ybf, N);

    const uint4* y0 = (const uint4*)ybf;
    const uint4* y1 = (const uint4*)(ybf + (size_t)N * 64);
    k_dot_h<<<8192, 256, 0, stream>>>(y0, src, dst, nsrc, ndst, out, E, 0);
    k_dot_h<<<8192, 256, 0, stream>>>(y1, src, dst, nsrc, ndst, out, E, 1);
}

// Round 13
// 831.353 us; speedup vs baseline: 1.1920x; 1.1920x over previous
//
#include <hip/hip_runtime.h>

#define EMB 128
#define CAP 128      // bucket capacity per node; deg~Poisson(32), P(>128)~1e-40
#define CSTRIDE 4    // counter padding stride in ints (4 counters per 64B line)
#define NPART 16     // dst-range partitions for the fill scatter (R10-proven)

typedef _Float16 half2_t __attribute__((ext_vector_type(2)));

// ---- bf16 helpers ---------------------------------------------------------
__device__ inline unsigned short f2bf(float f) {
    union { float f; unsigned u; } v; v.f = f;
    unsigned r = v.u + 0x7FFF + ((v.u >> 16) & 1);
    return (unsigned short)(r >> 16);
}
__device__ inline float bf2f(unsigned short b) {
    union { unsigned u; float f; } v; v.u = ((unsigned)b) << 16;
    return v.f;
}
// ---- f16 helpers ----------------------------------------------------------
__device__ inline unsigned short f2h(float f) {
    _Float16 h = (_Float16)f;
    return __builtin_bit_cast(unsigned short, h);
}
__device__ inline float fdot2u(unsigned a, unsigned b, float c) {
#if __has_builtin(__builtin_amdgcn_fdot2)
    return __builtin_amdgcn_fdot2(__builtin_bit_cast(half2_t, a),
                                  __builtin_bit_cast(half2_t, b), c, false);
#else
    half2_t ha = __builtin_bit_cast(half2_t, a);
    half2_t hb = __builtin_bit_cast(half2_t, b);
    return c + (float)ha.x * (float)hb.x + (float)ha.y * (float)hb.y;
#endif
}

// ---- partitioned bucket fill: each block owns a dst range (R10 config) ----
__global__ void k_fillb(const int* __restrict__ src, const int* __restrict__ dst,
                        int* __restrict__ cnt, int* __restrict__ cs, int E, int N) {
    const int part = blockIdx.x & (NPART - 1);
    const int lo = (int)(((long long)N * part) / NPART);
    const int hi = (int)(((long long)N * (part + 1)) / NPART);
    int i = (int)(blockIdx.x >> 4) * blockDim.x + threadIdx.x;
    const int stride = (int)(gridDim.x >> 4) * blockDim.x;
    for (; i < E; i += stride) {
        const int d = dst[i];
        if (d >= lo && d < hi) {
            const int s = src[i];
            int p = atomicAdd(&cnt[(size_t)d * CSTRIDE], 1);
            if (p < CAP) cs[((size_t)d << 7) + p] = s;
        }
    }
}

// ---- norm = 1/sqrt(max(deg,1)), norm2 = norm*norm -------------------------
__global__ void k_norm(const int* __restrict__ cnt, float* __restrict__ nrm,
                       float* __restrict__ nrm2, int N) {
    int i = blockIdx.x * blockDim.x + threadIdx.x;
    if (i < N) {
        float d = fmaxf((float)cnt[(size_t)i * CSTRIDE], 1.0f);
        float r = 1.0f / sqrtf(d);
        nrm[i] = r;
        nrm2[i] = r * r;
    }
}

// ---- X0 = emb * nrm -> bf16, dim-split layout [2][N][64] ------------------
__global__ void k_scale_bf(const float* __restrict__ x, const float* __restrict__ s,
                           ushort4* __restrict__ o, int N, int total4) {
    int idx = blockIdx.x * blockDim.x + threadIdx.x;
    if (idx < total4) {
        const int node = idx >> 5;   // 32 float4 per 128-float row
        const int q = idx & 31;
        const int h = q >> 4;        // which half
        const int qh = q & 15;       // float4 within half
        const float4 v = ((const float4*)x)[idx];
        const float f = s[node];
        ushort4 r;
        r.x = f2bf(v.x * f); r.y = f2bf(v.y * f);
        r.z = f2bf(v.z * f); r.w = f2bf(v.w * f);
        o[((size_t)h * N + node) * 16 + qh] = r;
    }
}

// ---- hop on one 64-dim half, bf16 in -> bf16 out: 16 lanes per node -------
__global__ __launch_bounds__(256) void k_hop_bb(const ushort4* __restrict__ in_h,
                                                const float* __restrict__ oscale,
                                                const int* __restrict__ cnt,
                                                const int* __restrict__ csr,
                                                ushort4* __restrict__ out_h, int N) {
    const int l = threadIdx.x & 15;
    int nd = (blockIdx.x * blockDim.x + threadIdx.x) >> 4;
    const int nnd = (gridDim.x * blockDim.x) >> 4;
    for (int i = nd; i < N; i += nnd) {
        const int jb = i << 7;
        const int je = jb + min(cnt[(size_t)i * CSTRIDE], CAP);
        float ax = 0.f, ay = 0.f, az = 0.f, aw = 0.f;
        int j = jb;
        for (; j + 4 <= je; j += 4) {
            const int c0 = csr[j], c1 = csr[j + 1], c2 = csr[j + 2], c3 = csr[j + 3];
            const ushort4 v0 = in_h[(size_t)c0 * 16 + l];
            const ushort4 v1 = in_h[(size_t)c1 * 16 + l];
            const ushort4 v2 = in_h[(size_t)c2 * 16 + l];
            const ushort4 v3 = in_h[(size_t)c3 * 16 + l];
            ax += bf2f(v0.x) + bf2f(v1.x) + bf2f(v2.x) + bf2f(v3.x);
            ay += bf2f(v0.y) + bf2f(v1.y) + bf2f(v2.y) + bf2f(v3.y);
            az += bf2f(v0.z) + bf2f(v1.z) + bf2f(v2.z) + bf2f(v3.z);
            aw += bf2f(v0.w) + bf2f(v1.w) + bf2f(v2.w) + bf2f(v3.w);
        }
        for (; j < je; ++j) {
            const ushort4 v = in_h[(size_t)csr[j] * 16 + l];
            ax += bf2f(v.x); ay += bf2f(v.y); az += bf2f(v.z); aw += bf2f(v.w);
        }
        const float s = oscale[i];
        ushort4 o;
        o.x = f2bf(ax * s); o.y = f2bf(ay * s);
        o.z = f2bf(az * s); o.w = f2bf(aw * s);
        out_h[(size_t)i * 16 + l] = o;
    }
}

// ---- hop on one half, bf16 in -> f32 out ----------------------------------
__global__ __launch_bounds__(256) void k_hop_bf(const ushort4* __restrict__ in_h,
                                                const float* __restrict__ oscale,
                                                const int* __restrict__ cnt,
                                                const int* __restrict__ csr,
                                                float4* __restrict__ out_h, int N) {
    const int l = threadIdx.x & 15;
    int nd = (blockIdx.x * blockDim.x + threadIdx.x) >> 4;
    const int nnd = (gridDim.x * blockDim.x) >> 4;
    for (int i = nd; i < N; i += nnd) {
        const int jb = i << 7;
        const int je = jb + min(cnt[(size_t)i * CSTRIDE], CAP);
        float ax = 0.f, ay = 0.f, az = 0.f, aw = 0.f;
        int j = jb;
        for (; j + 4 <= je; j += 4) {
            const int c0 = csr[j], c1 = csr[j + 1], c2 = csr[j + 2], c3 = csr[j + 3];
            const ushort4 v0 = in_h[(size_t)c0 * 16 + l];
            const ushort4 v1 = in_h[(size_t)c1 * 16 + l];
            const ushort4 v2 = in_h[(size_t)c2 * 16 + l];
            const ushort4 v3 = in_h[(size_t)c3 * 16 + l];
            ax += bf2f(v0.x) + bf2f(v1.x) + bf2f(v2.x) + bf2f(v3.x);
            ay += bf2f(v0.y) + bf2f(v1.y) + bf2f(v2.y) + bf2f(v3.y);
            az += bf2f(v0.z) + bf2f(v1.z) + bf2f(v2.z) + bf2f(v3.z);
            aw += bf2f(v0.w) + bf2f(v1.w) + bf2f(v2.w) + bf2f(v3.w);
        }
        for (; j < je; ++j) {
            const ushort4 v = in_h[(size_t)csr[j] * 16 + l];
            ax += bf2f(v.x); ay += bf2f(v.y); az += bf2f(v.z); aw += bf2f(v.w);
        }
        const float s = oscale[i];
        float4 o; o.x = ax * s; o.y = ay * s; o.z = az * s; o.w = aw * s;
        out_h[(size_t)i * 16 + l] = o;
    }
}

// ---- linear: y(f16, split) = h(split f32) @ W.T + bias --------------------
#define LIN_RT 128
__global__ __launch_bounds__(256) void k_lin(const float* __restrict__ H2,
                                             const float* __restrict__ W,
                                             const float* __restrict__ bias,
                                             unsigned short* __restrict__ y, int N) {
    __shared__ float Wl[128 * 128];
    __shared__ float hl[LIN_RT * 129];
    const int t = threadIdx.x;
    const int r0g = blockIdx.x * LIN_RT;
    const int nv = min(LIN_RT, N - r0g);
    const float* H2_0 = H2;
    const float* H2_1 = H2 + (size_t)N * 64;

    {
        const int j = t & 127, k0 = (t >> 7) * 64;
        #pragma unroll
        for (int c = 0; c < 16; ++c) {
            const float4 v = *(const float4*)&W[j * 128 + k0 + 4 * c];
            Wl[(k0 + 4 * c + 0) * 128 + j] = v.x;
            Wl[(k0 + 4 * c + 1) * 128 + j] = v.y;
            Wl[(k0 + 4 * c + 2) * 128 + j] = v.z;
            Wl[(k0 + 4 * c + 3) * 128 + j] = v.w;
        }
    }
    for (int e = t; e < LIN_RT * 32; e += 256) {
        const int r = e >> 5, q = e & 31;
        float4 v; v.x = 0.f; v.y = 0.f; v.z = 0.f; v.w = 0.f;
        if (r < nv) {
            if (q < 16) v = *(const float4*)&H2_0[(size_t)(r0g + r) * 64 + 4 * q];
            else        v = *(const float4*)&H2_1[(size_t)(r0g + r) * 64 + 4 * (q - 16)];
        }
        hl[r * 129 + 4 * q + 0] = v.x;
        hl[r * 129 + 4 * q + 1] = v.y;
        hl[r * 129 + 4 * q + 2] = v.z;
        hl[r * 129 + 4 * q + 3] = v.w;
    }
    __syncthreads();

    const int tc = t & 15, tr = t >> 4;
    const int rb = tr * 8;
    const int j0 = 4 * tc, j1 = 64 + 4 * tc;
    float acc[8][8];
    #pragma unroll
    for (int a = 0; a < 8; ++a)
        #pragma unroll
        for (int b = 0; b < 8; ++b) acc[a][b] = 0.f;

    #pragma unroll 2
    for (int k = 0; k < 128; ++k) {
        const float4 w0 = *(const float4*)&Wl[k * 128 + j0];
        const float4 w1 = *(const float4*)&Wl[k * 128 + j1];
        float hreg[8];
        #pragma unroll
        for (int a = 0; a < 8; ++a) hreg[a] = hl[(rb + a) * 129 + k];
        #pragma unroll
        for (int a = 0; a < 8; ++a) {
            acc[a][0] += hreg[a] * w0.x; acc[a][1] += hreg[a] * w0.y;
            acc[a][2] += hreg[a] * w0.z; acc[a][3] += hreg[a] * w0.w;
            acc[a][4] += hreg[a] * w1.x; acc[a][5] += hreg[a] * w1.y;
            acc[a][6] += hreg[a] * w1.z; acc[a][7] += hreg[a] * w1.w;
        }
    }

    ushort4* y0 = (ushort4*)y;
    ushort4* y1 = (ushort4*)(y + (size_t)N * 64);
    const float4 b0 = *(const float4*)&bias[j0];
    const float4 b1 = *(const float4*)&bias[j1];
    #pragma unroll
    for (int a = 0; a < 8; ++a) {
        const int r = rb + a;
        if (r < nv) {
            ushort4 p0, p1;
            p0.x = f2h(acc[a][0] + b0.x); p0.y = f2h(acc[a][1] + b0.y);
            p0.z = f2h(acc[a][2] + b0.z); p0.w = f2h(acc[a][3] + b0.w);
            p1.x = f2h(acc[a][4] + b1.x); p1.y = f2h(acc[a][5] + b1.y);
            p1.z = f2h(acc[a][6] + b1.z); p1.w = f2h(acc[a][7] + b1.w);
            y0[(size_t)(r0g + r) * 16 + tc] = p0;
            y1[(size_t)(r0g + r) * 16 + tc] = p1;
        }
    }
}

// ---- edge dots on one 64-dim half: 8 lanes x uint4 per edge, 8 edges/wave -
__global__ __launch_bounds__(256) void k_dot_h(const uint4* __restrict__ yh,
                                               const int* __restrict__ src,
                                               const int* __restrict__ dst,
                                               const int* __restrict__ nsrc,
                                               const int* __restrict__ ndst,
                                               float* __restrict__ out, int E,
                                               int accum) {
    const int lane = threadIdx.x & 63;
    const int grp = lane >> 3;           // 8 edges per wave
    const int l = lane & 7;              // 8 lanes per edge (8 x 16B = 128B row)
    int w = (blockIdx.x * blockDim.x + threadIdx.x) >> 6;
    const int nw = (gridDim.x * blockDim.x) >> 6;
    const int total = 2 * E;
    const int Q = (total + 7) >> 3;
    for (int q = w; q < Q; q += nw) {
        const int e = 8 * q + grp;
        if (e < total) {
            int s, d;
            if (e < E) { s = src[e]; d = dst[e]; }
            else       { s = nsrc[e - E]; d = ndst[e - E]; }
            const uint4 a = yh[(size_t)s * 8 + l];
            const uint4 c = yh[(size_t)d * 8 + l];
            float v0 = fdot2u(a.x, c.x, 0.f);
            float v1 = fdot2u(a.y, c.y, 0.f);
            v0 = fdot2u(a.z, c.z, v0);
            v1 = fdot2u(a.w, c.w, v1);
            float v = v0 + v1;
            v += __shfl_xor(v, 4);
            v += __shfl_xor(v, 2);
            v += __shfl_xor(v, 1);
            if (l == 0) out[e] = accum ? (out[e] + v) : v;
        }
    }
}

extern "C" void kernel_launch(void* const* d_in, const int* in_sizes, int n_in,
                              void* d_out, int out_size, void* d_ws, size_t ws_size,
                              hipStream_t stream) {
    const float* emb = (const float*)d_in[0];
    const float* W   = (const float*)d_in[1];
    const float* bia = (const float*)d_in[2];
    const int* src   = (const int*)d_in[3];
    const int* dst   = (const int*)d_in[4];
    const int* nsrc  = (const int*)d_in[5];
    const int* ndst  = (const int*)d_in[6];
    const int N = in_sizes[0] / EMB;
    const int E = in_sizes[3];
    float* out = (float*)d_out;

    const size_t szBF = (size_t)N * EMB * sizeof(unsigned short);  // 25.6 MB
    const size_t szF  = (size_t)N * EMB * sizeof(float);           // 51.2 MB
    const size_t szCS = (size_t)N * CAP * sizeof(int);             // 51.2 MB
    const size_t szN  = (size_t)N * sizeof(int);

    char* p = (char*)d_ws;
    auto alloc = [&](size_t bytes) { char* r = p; p += (bytes + 255) & ~(size_t)255; return r; };
    unsigned short* X0  = (unsigned short*)alloc(szBF);  // [2][N][64] bf16; y overlays
    unsigned short* H1  = (unsigned short*)alloc(szBF);  // [2][N][64] bf16
    float*          H2  = (float*)alloc(szF);            // [2][N][64] f32
    int*   csr  = (int*)alloc(szCS);                     // bucket CSR
    float* nrm  = (float*)alloc(szN);
    float* nrm2 = (float*)alloc(szN);
    int*   cnt  = (int*)alloc(szN * CSTRIDE);            // padded counters
    unsigned short* ybf = X0;  // X0 dead after hop1 passes

    hipMemsetAsync(cnt, 0, szN * CSTRIDE, stream);
    k_fillb<<<2048, 256, 0, stream>>>(src, dst, cnt, csr, E, N);
    k_norm<<<(N + 255) / 256, 256, 0, stream>>>(cnt, nrm, nrm2, N);

    const int total4 = N * 32;
    k_scale_bf<<<(total4 + 255) / 256, 256, 0, stream>>>(emb, nrm, (ushort4*)X0, N, total4);

    const int ND_BLOCKS = (N * 16 + 255) / 256;
    const ushort4* X0u = (const ushort4*)X0;
    ushort4* H1u = (ushort4*)H1;
    float4* H2u = (float4*)H2;
    for (int h = 0; h < 2; ++h)
        k_hop_bb<<<ND_BLOCKS, 256, 0, stream>>>(X0u + (size_t)h * N * 16, nrm2, cnt, csr,
                                                H1u + (size_t)h * N * 16, N);
    for (int h = 0; h < 2; ++h)
        k_hop_bf<<<ND_BLOCKS, 256, 0, stream>>>((const ushort4*)H1 + (size_t)h * N * 16,
                                                nrm, cnt, csr,
                                                H2u + (size_t)h * N * 16, N);

    k_lin<<<(N + LIN_RT - 1) / LIN_RT, 256, 0, stream>>>(H2, W, bia, ybf, N);

    const uint4* y0 = (const uint4*)ybf;
    const uint4* y1 = (const uint4*)(ybf + (size_t)N * 64);
    k_dot_h<<<8192, 256, 0, stream>>>(y0, src, dst, nsrc, ndst, out, E, 0);
    k_dot_h<<<8192, 256, 0, stream>>>(y1, src, dst, nsrc, ndst, out, E, 1);
}